// Round 1
// baseline (426.905 us; speedup 1.0000x reference)
//
#include <hip/hip_runtime.h>
#include <math.h>

#define NB   32
#define CCH  64
#define HWD  1024
#define CHW  65536     // C*H*W per sample
#define EPSV 1e-5f

// ---------------------------------------------------------------------------
// Kernel 1: partial LN stats. grid (chunk=8, which=3, n=32), block 256.
// Each block reduces 8192 elements -> (sum, sumsq) partial.
// ---------------------------------------------------------------------------
__global__ __launch_bounds__(256)
void k_stats(const float* __restrict__ q, const float* __restrict__ k,
             const float* __restrict__ v, float* __restrict__ part)
{
    const int chunk = blockIdx.x, which = blockIdx.y, n = blockIdx.z;
    const float* x = (which == 0) ? q : (which == 1 ? k : v);
    const float4* x4 = (const float4*)(x + (size_t)n * CHW) + chunk * 2048;
    float s = 0.f, ss = 0.f;
#pragma unroll
    for (int i = 0; i < 8; ++i) {
        float4 t = x4[threadIdx.x + i * 256];
        s  += t.x + t.y + t.z + t.w;
        ss += t.x * t.x + t.y * t.y + t.z * t.z + t.w * t.w;
    }
    __shared__ float rs[256], rss[256];
    rs[threadIdx.x] = s; rss[threadIdx.x] = ss;
    __syncthreads();
    for (int off = 128; off > 0; off >>= 1) {
        if (threadIdx.x < off) {
            rs[threadIdx.x]  += rs[threadIdx.x + off];
            rss[threadIdx.x] += rss[threadIdx.x + off];
        }
        __syncthreads();
    }
    if (threadIdx.x == 0) {
        const int b = (n * 3 + which) * 8 + chunk;
        part[b * 2 + 0] = rs[0];
        part[b * 2 + 1] = rss[0];
    }
}

// ---------------------------------------------------------------------------
// Kernel 2: finish stats + LayerNorm + 1x1-conv projections (Q,K,V).
// grid (pt=16, n=32), block 256. Each block: 64 pixels of one sample.
//   xn[t][c][p]  normalized inputs in LDS (pad 68 keeps float4 align + banks)
//   wt[t][c][o]  transposed proj weights in LDS (float4 over o)
// Also writes qn (normalized query) for the residual.
// ---------------------------------------------------------------------------
__global__ __launch_bounds__(256)
void k_proj(const float* __restrict__ q,  const float* __restrict__ k,  const float* __restrict__ v,
            const float* __restrict__ w1, const float* __restrict__ b1,
            const float* __restrict__ w2, const float* __restrict__ b2,
            const float* __restrict__ w3, const float* __restrict__ b3,
            const float* __restrict__ wq, const float* __restrict__ bq,
            const float* __restrict__ wk, const float* __restrict__ bk,
            const float* __restrict__ wv, const float* __restrict__ bv,
            const float* __restrict__ part,
            float* __restrict__ qn, float* __restrict__ pqo,
            float* __restrict__ pko, float* __restrict__ pvo)
{
    __shared__ float xn[3][64][68];
    __shared__ float wt[3][64][68];
    __shared__ float musd[6];
    const int pt = blockIdx.x, n = blockIdx.y;
    const int t = threadIdx.x;

    // finish the two-stage LN stats (3 tensors)
    if (t < 3) {
        float s = 0.f, ss = 0.f;
#pragma unroll
        for (int cidx = 0; cidx < 8; ++cidx) {
            const int b = (n * 3 + t) * 8 + cidx;
            s  += part[b * 2 + 0];
            ss += part[b * 2 + 1];
        }
        const float mu = s * (1.0f / CHW);
        musd[t * 2 + 0] = mu;
        musd[t * 2 + 1] = rsqrtf(ss * (1.0f / CHW) - mu * mu + EPSV);
    }

    // stage transposed weights: w[o][c] -> wt[c][o]
    const float* pw[3] = {wq, wk, wv};
#pragma unroll
    for (int tt = 0; tt < 3; ++tt)
        for (int idx = t; idx < 4096; idx += 256) {
            const int o = idx >> 6, c = idx & 63;
            wt[tt][c][o] = pw[tt][idx];
        }
    __syncthreads();   // musd ready

    // normalize inputs into LDS (and write qn for residual)
    const float* src[3] = {q, k, v};
    const float* lw[3]  = {w1, w2, w3};
    const float* lb[3]  = {b1, b2, b3};
#pragma unroll
    for (int tt = 0; tt < 3; ++tt) {
        const float mu = musd[tt * 2], is = musd[tt * 2 + 1];
        for (int idx = t; idx < 1024; idx += 256) {      // 4096 elems as float4
            const int c = idx >> 4, p4 = idx & 15;
            const int gi = c * HWD + pt * 64 + p4 * 4;
            float4 xv = *(const float4*)&src[tt][(size_t)n * CHW + gi];
            float4 w4 = *(const float4*)&lw[tt][gi];
            float4 b4 = *(const float4*)&lb[tt][gi];
            float4 r;
            r.x = (xv.x - mu) * is * w4.x + b4.x;
            r.y = (xv.y - mu) * is * w4.y + b4.y;
            r.z = (xv.z - mu) * is * w4.z + b4.z;
            r.w = (xv.w - mu) * is * w4.w + b4.w;
            *(float4*)&xn[tt][c][p4 * 4] = r;
            if (tt == 0) *(float4*)&qn[(size_t)n * CHW + gi] = r;
        }
    }
    __syncthreads();

    // projections: out[o][p] = b[o] + sum_c w[o][c]*xn[c][p]
    const int p  = t & 63;
    const int ob = (t >> 6) * 16;
    const float* pbias[3] = {bq, bk, bv};
    float* dst[3] = {pqo, pko, pvo};
#pragma unroll
    for (int tt = 0; tt < 3; ++tt) {
        float acc[16];
#pragma unroll
        for (int i = 0; i < 16; ++i) acc[i] = pbias[tt][ob + i];
#pragma unroll 4
        for (int c = 0; c < 64; ++c) {
            const float xv = xn[tt][c][p];
#pragma unroll
            for (int o4 = 0; o4 < 4; ++o4) {
                float4 w4 = *(const float4*)&wt[tt][c][ob + o4 * 4];
                acc[o4 * 4 + 0] += w4.x * xv;
                acc[o4 * 4 + 1] += w4.y * xv;
                acc[o4 * 4 + 2] += w4.z * xv;
                acc[o4 * 4 + 3] += w4.w * xv;
            }
        }
#pragma unroll
        for (int i = 0; i < 16; ++i)
            dst[tt][(size_t)n * CHW + (ob + i) * HWD + pt * 64 + p] = acc[i];
    }
}

// ---------------------------------------------------------------------------
// Kernel 3: fused attention per (jb, n): 32 output columns of one sample.
//   S[32][1028] : full score tile (i=0..1023 per column), padded for banks+align
//   aux        : Q tile [64][36] (phase 1) then V chunks [64][68] (phase 4)
// phases: QK^T -> column softmax -> attn write -> PV + residual.
// ---------------------------------------------------------------------------
__global__ __launch_bounds__(256, 1)
void k_attn(const float* __restrict__ pq, const float* __restrict__ pk,
            const float* __restrict__ pv, const float* __restrict__ qn,
            float* __restrict__ xout, float* __restrict__ attn)
{
    __shared__ float S[32 * 1028 + 64 * 68];
    float* aux = S + 32 * 1028;
    const int jb = blockIdx.x, n = blockIdx.y;
    const int t = threadIdx.x;
    const size_t nb = (size_t)n * CHW;

    // stage Q tile: aux[c*36 + j] = Qp[n][c][jb*32+j]
    for (int idx = t; idx < 2048; idx += 256) {
        const int c = idx >> 5, j = idx & 31;
        aux[c * 36 + j] = pq[nb + c * HWD + jb * 32 + j];
    }
    __syncthreads();

    // phase 1: S[j][i] = (1/8) sum_c K[c][i] * Q[c][j]
#pragma unroll
    for (int pass = 0; pass < 2; ++pass) {
        const int i0 = pass * 512 + t;
        float a0[32], a1[32];
#pragma unroll
        for (int j = 0; j < 32; ++j) { a0[j] = 0.f; a1[j] = 0.f; }
#pragma unroll 2
        for (int c = 0; c < 64; ++c) {
            const float k0 = pk[nb + c * HWD + i0];
            const float k1 = pk[nb + c * HWD + i0 + 256];
#pragma unroll
            for (int j4 = 0; j4 < 8; ++j4) {
                float4 qv = *(const float4*)&aux[c * 36 + j4 * 4];
                a0[j4 * 4 + 0] += k0 * qv.x; a0[j4 * 4 + 1] += k0 * qv.y;
                a0[j4 * 4 + 2] += k0 * qv.z; a0[j4 * 4 + 3] += k0 * qv.w;
                a1[j4 * 4 + 0] += k1 * qv.x; a1[j4 * 4 + 1] += k1 * qv.y;
                a1[j4 * 4 + 2] += k1 * qv.z; a1[j4 * 4 + 3] += k1 * qv.w;
            }
        }
#pragma unroll
        for (int j = 0; j < 32; ++j) {
            S[j * 1028 + i0]       = a0[j] * 0.125f;
            S[j * 1028 + i0 + 256] = a1[j] * 0.125f;
        }
    }
    __syncthreads();

    // phase 2: softmax over i within each column j (= LDS row j)
    {
        const int j = t >> 3, sub = t & 7;
        float* row = S + j * 1028;
        const int ii = sub ^ (j & 7);          // bank de-phase, still partitions i
        float m = -1e30f;
        for (int i = ii; i < 1024; i += 8) m = fmaxf(m, row[i]);
        m = fmaxf(m, __shfl_xor(m, 1));
        m = fmaxf(m, __shfl_xor(m, 2));
        m = fmaxf(m, __shfl_xor(m, 4));
        float sum = 0.f;
        for (int i = ii; i < 1024; i += 8) {
            const float e = __expf(row[i] - m);
            row[i] = e;
            sum += e;
        }
        sum += __shfl_xor(sum, 1);
        sum += __shfl_xor(sum, 2);
        sum += __shfl_xor(sum, 4);
        const float inv = 1.0f / sum;
        for (int i = ii; i < 1024; i += 8) row[i] *= inv;
    }
    __syncthreads();

    // phase 3: write attn[n][i][jb*32+j] (coalesced 128B rows)
    {
        float* ao = attn + (size_t)n * HWD * HWD + jb * 32;
        for (int idx = t; idx < 32768; idx += 256) {
            const int i = idx >> 5, j = idx & 31;
            ao[(size_t)i * HWD + j] = S[j * 1028 + i];
        }
    }

    // phase 4: out[c][j] = sum_i V[c][i] * S[j][i]; fused residual + x write
    {
        const int jj = (t & 7) * 4;
        const int c0 = (t >> 3) * 2;
        float acc[2][4] = {{0.f,0.f,0.f,0.f},{0.f,0.f,0.f,0.f}};
        for (int ib = 0; ib < 16; ++ib) {
            __syncthreads();
            for (int idx = t; idx < 1024; idx += 256) {   // stage V chunk (float4)
                const int c = idx >> 4, il4 = idx & 15;
                *(float4*)&aux[c * 68 + il4 * 4] =
                    *(const float4*)&pv[nb + c * HWD + ib * 64 + il4 * 4];
            }
            __syncthreads();
#pragma unroll
            for (int il4 = 0; il4 < 16; ++il4) {
                float4 v0 = *(const float4*)&aux[c0 * 68 + il4 * 4];
                float4 v1 = *(const float4*)&aux[(c0 + 1) * 68 + il4 * 4];
#pragma unroll
                for (int jx = 0; jx < 4; ++jx) {
                    float4 s4 = *(const float4*)&S[(jj + jx) * 1028 + ib * 64 + il4 * 4];
                    acc[0][jx] += v0.x * s4.x + v0.y * s4.y + v0.z * s4.z + v0.w * s4.w;
                    acc[1][jx] += v1.x * s4.x + v1.y * s4.y + v1.z * s4.z + v1.w * s4.w;
                }
            }
        }
#pragma unroll
        for (int cc = 0; cc < 2; ++cc) {
            const int c = c0 + cc;
            const size_t o = nb + (size_t)c * HWD + jb * 32 + jj;
            float4 q4 = *(const float4*)&qn[o];
            float4 r;
            r.x = acc[cc][0] + q4.x;
            r.y = acc[cc][1] + q4.y;
            r.z = acc[cc][2] + q4.z;
            r.w = acc[cc][3] + q4.w;
            *(float4*)&xout[o] = r;
        }
    }
}

// ---------------------------------------------------------------------------
extern "C" void kernel_launch(void* const* d_in, const int* in_sizes, int n_in,
                              void* d_out, int out_size, void* d_ws, size_t ws_size,
                              hipStream_t stream)
{
    const float* q  = (const float*)d_in[0];
    const float* k  = (const float*)d_in[1];
    const float* v  = (const float*)d_in[2];
    const float* w1 = (const float*)d_in[3];
    const float* b1 = (const float*)d_in[4];
    const float* w2 = (const float*)d_in[5];
    const float* b2 = (const float*)d_in[6];
    const float* w3 = (const float*)d_in[7];
    const float* b3 = (const float*)d_in[8];
    const float* wq = (const float*)d_in[9];
    const float* bq = (const float*)d_in[10];
    const float* wk = (const float*)d_in[11];
    const float* bk = (const float*)d_in[12];
    const float* wv = (const float*)d_in[13];
    const float* bv = (const float*)d_in[14];

    // ws layout (floats): [0,1536) stats partials; qn @4096; then Pq,Pk,Pv.
    // total = 4096 + 4*2097152 floats = 33.6 MB
    float* ws   = (float*)d_ws;
    float* part = ws;
    float* qn   = ws + 4096;
    float* pq   = qn + 2097152;
    float* pk   = pq + 2097152;
    float* pv   = pk + 2097152;

    float* xout = (float*)d_out;            // (N, C*H*W) = 2,097,152 floats
    float* attn = xout + 2097152;           // (N, HW, HW) = 33,554,432 floats

    k_stats<<<dim3(8, 3, 32), 256, 0, stream>>>(q, k, v, part);
    k_proj<<<dim3(16, 32), 256, 0, stream>>>(q, k, v, w1, b1, w2, b2, w3, b3,
                                             wq, bq, wk, bk, wv, bv,
                                             part, qn, pq, pk, pv);
    k_attn<<<dim3(32, 32), 256, 0, stream>>>(pq, pk, pv, qn, xout, attn);
}

// Round 2
// 109.026 us; speedup vs baseline: 3.9156x; 3.9156x over previous
//
#include <hip/hip_runtime.h>
#include <math.h>

#define NB   32
#define CCH  64
#define HWD  1024
#define CHW  65536     // C*H*W per sample
#define EPSV 1e-5f

typedef __attribute__((ext_vector_type(8))) short bf16x8;
typedef __attribute__((ext_vector_type(4))) float f32x4;

__device__ __forceinline__ unsigned f2b(float x) {
    union { float f; unsigned u; } v; v.f = x;
    return (v.u + 0x7fffu + ((v.u >> 16) & 1u)) >> 16;   // RNE bf16 bits
}

// ---------------------------------------------------------------------------
// Kernel 1: partial LN stats. grid (chunk=8, which=3, n=32), block 256.
// ---------------------------------------------------------------------------
__global__ __launch_bounds__(256)
void k_stats(const float* __restrict__ q, const float* __restrict__ k,
             const float* __restrict__ v, float* __restrict__ part)
{
    const int chunk = blockIdx.x, which = blockIdx.y, n = blockIdx.z;
    const float* x = (which == 0) ? q : (which == 1 ? k : v);
    const float4* x4 = (const float4*)(x + (size_t)n * CHW) + chunk * 2048;
    float s = 0.f, ss = 0.f;
#pragma unroll
    for (int i = 0; i < 8; ++i) {
        float4 t = x4[threadIdx.x + i * 256];
        s  += t.x + t.y + t.z + t.w;
        ss += t.x * t.x + t.y * t.y + t.z * t.z + t.w * t.w;
    }
    __shared__ float rs[256], rss[256];
    rs[threadIdx.x] = s; rss[threadIdx.x] = ss;
    __syncthreads();
    for (int off = 128; off > 0; off >>= 1) {
        if (threadIdx.x < off) {
            rs[threadIdx.x]  += rs[threadIdx.x + off];
            rss[threadIdx.x] += rss[threadIdx.x + off];
        }
        __syncthreads();
    }
    if (threadIdx.x == 0) {
        const int b = (n * 3 + which) * 8 + chunk;
        part[b * 2 + 0] = rs[0];
        part[b * 2 + 1] = rss[0];
    }
}

// ---------------------------------------------------------------------------
// Kernel 2: finish stats + LayerNorm + 1x1-conv projections (Q,K,V).
// grid (pt=16, n=32), block 256.
// ---------------------------------------------------------------------------
__global__ __launch_bounds__(256)
void k_proj(const float* __restrict__ q,  const float* __restrict__ k,  const float* __restrict__ v,
            const float* __restrict__ w1, const float* __restrict__ b1,
            const float* __restrict__ w2, const float* __restrict__ b2,
            const float* __restrict__ w3, const float* __restrict__ b3,
            const float* __restrict__ wq, const float* __restrict__ bq,
            const float* __restrict__ wk, const float* __restrict__ bk,
            const float* __restrict__ wv, const float* __restrict__ bv,
            const float* __restrict__ part,
            float* __restrict__ qn, float* __restrict__ pqo,
            float* __restrict__ pko, float* __restrict__ pvo)
{
    __shared__ float xn[3][64][68];
    __shared__ float wt[3][64][68];
    __shared__ float musd[6];
    const int pt = blockIdx.x, n = blockIdx.y;
    const int t = threadIdx.x;

    if (t < 3) {
        float s = 0.f, ss = 0.f;
#pragma unroll
        for (int cidx = 0; cidx < 8; ++cidx) {
            const int b = (n * 3 + t) * 8 + cidx;
            s  += part[b * 2 + 0];
            ss += part[b * 2 + 1];
        }
        const float mu = s * (1.0f / CHW);
        musd[t * 2 + 0] = mu;
        musd[t * 2 + 1] = rsqrtf(ss * (1.0f / CHW) - mu * mu + EPSV);
    }

    const float* pw[3] = {wq, wk, wv};
#pragma unroll
    for (int tt = 0; tt < 3; ++tt)
        for (int idx = t; idx < 4096; idx += 256) {
            const int o = idx >> 6, c = idx & 63;
            wt[tt][c][o] = pw[tt][idx];
        }
    __syncthreads();

    const float* src[3] = {q, k, v};
    const float* lw[3]  = {w1, w2, w3};
    const float* lb[3]  = {b1, b2, b3};
#pragma unroll
    for (int tt = 0; tt < 3; ++tt) {
        const float mu = musd[tt * 2], is = musd[tt * 2 + 1];
        for (int idx = t; idx < 1024; idx += 256) {
            const int c = idx >> 4, p4 = idx & 15;
            const int gi = c * HWD + pt * 64 + p4 * 4;
            float4 xv = *(const float4*)&src[tt][(size_t)n * CHW + gi];
            float4 w4 = *(const float4*)&lw[tt][gi];
            float4 b4 = *(const float4*)&lb[tt][gi];
            float4 r;
            r.x = (xv.x - mu) * is * w4.x + b4.x;
            r.y = (xv.y - mu) * is * w4.y + b4.y;
            r.z = (xv.z - mu) * is * w4.z + b4.z;
            r.w = (xv.w - mu) * is * w4.w + b4.w;
            *(float4*)&xn[tt][c][p4 * 4] = r;
            if (tt == 0) *(float4*)&qn[(size_t)n * CHW + gi] = r;
        }
    }
    __syncthreads();

    const int p  = t & 63;
    const int ob = (t >> 6) * 16;
    const float* pbias[3] = {bq, bk, bv};
    float* dst[3] = {pqo, pko, pvo};
#pragma unroll
    for (int tt = 0; tt < 3; ++tt) {
        float acc[16];
#pragma unroll
        for (int i = 0; i < 16; ++i) acc[i] = pbias[tt][ob + i];
#pragma unroll 4
        for (int c = 0; c < 64; ++c) {
            const float xv = xn[tt][c][p];
#pragma unroll
            for (int o4 = 0; o4 < 4; ++o4) {
                float4 w4 = *(const float4*)&wt[tt][c][ob + o4 * 4];
                acc[o4 * 4 + 0] += w4.x * xv;
                acc[o4 * 4 + 1] += w4.y * xv;
                acc[o4 * 4 + 2] += w4.z * xv;
                acc[o4 * 4 + 3] += w4.w * xv;
            }
        }
#pragma unroll
        for (int i = 0; i < 16; ++i)
            dst[tt][(size_t)n * CHW + (ob + i) * HWD + pt * 64 + p] = acc[i];
    }
}

// ---------------------------------------------------------------------------
// Kernel 3 (MFMA): fused attention. One block per (n, 64-column tile).
// 512 threads = 8 waves. Wave w computes S rows i in [w*128, w*128+128).
//   LDS: p_lds  [64 j][1024 i] bf16, row 2048B, XOR-swizzled (131072 B @0)
//        v_lds  [64 c][136 i]  bf16 chunk                    (17408 B @131072)
//        q_lds  [64 j][72 c]   bf16 (Q^T, pre-scaled 1/8)    (9216 B  @148480)
//        wred   [8][64] f32                                  (2048 B  @157696)
//        colv   [64]    f32                                  (256 B   @159744)
// MFMA 16x16x32 bf16: A lane l -> A[l&15][(l>>4)*8+e]; B lane l -> B[(l>>4)*8+e][l&15];
// D lane l, reg r -> D[(l>>4)*4+r][l&15]  (C/D layout HW-verified per guide §3).
// ---------------------------------------------------------------------------
__global__ __launch_bounds__(512, 2)
void k_attn2(const float* __restrict__ pq, const float* __restrict__ pk,
             const float* __restrict__ pv, const float* __restrict__ qn,
             float* __restrict__ xout, float* __restrict__ attn)
{
    __shared__ __align__(16) char smem[160000];
    short* p_lds = (short*)smem;
    short* v_lds = (short*)(smem + 131072);
    short* q_lds = (short*)(smem + 148480);
    float* wred  = (float*)(smem + 157696);
    float* colv  = (float*)(smem + 159744);

    // XCD-bijective swizzle: 512 wgs = 8 XCDs x 64; 4 consecutive samples/XCD
    const int wg  = blockIdx.x;
    const int xcd = wg & 7, lid = wg >> 3;
    const int n   = xcd * 4 + (lid >> 4);
    const int jb  = lid & 15;
    const size_t nb = (size_t)n * CHW;
    const int t = threadIdx.x;
    const int w = t >> 6;
    const int l = t & 63;
    const int l15 = l & 15, lg = l >> 4;
    const int ibase = w * 128;

    // ---- stage Q^T (scaled by 1/8, exact pow2) : q_lds[j][c]
    {
        const int j = t & 63;
#pragma unroll
        for (int p8 = 0; p8 < 4; ++p8) {
            const int c2 = (t >> 6) + p8 * 8;           // c-pair 0..31
            float a = pq[nb + (size_t)(2 * c2)     * HWD + jb * 64 + j] * 0.125f;
            float b = pq[nb + (size_t)(2 * c2 + 1) * HWD + jb * 64 + j] * 0.125f;
            *(unsigned*)&q_lds[j * 72 + c2 * 2] = (f2b(b) << 16) | f2b(a);
        }
    }
    __syncthreads();

    // ---- phase 1: S = K^T Q   (acc[f][jt], f = i-frag 0..7, jt = j-frag 0..3)
    f32x4 acc[8][4] = {};
#pragma unroll
    for (int ks = 0; ks < 2; ++ks) {
        bf16x8 bq[4];
#pragma unroll
        for (int jt = 0; jt < 4; ++jt)
            bq[jt] = *(const bf16x8*)&q_lds[(jt * 16 + l15) * 72 + ks * 32 + lg * 8];
#pragma unroll
        for (int half = 0; half < 2; ++half) {
            float kv[4][8];
#pragma unroll
            for (int f4 = 0; f4 < 4; ++f4) {
                const int i = ibase + (half * 4 + f4) * 16 + l15;
                const float* kp = pk + nb + (size_t)(ks * 32 + lg * 8) * HWD + i;
#pragma unroll
                for (int e = 0; e < 8; ++e) kv[f4][e] = kp[(size_t)e * HWD];
            }
#pragma unroll
            for (int f4 = 0; f4 < 4; ++f4) {
                bf16x8 af;
#pragma unroll
                for (int e = 0; e < 8; ++e) af[e] = (short)f2b(kv[f4][e]);
                const int f = half * 4 + f4;
#pragma unroll
                for (int jt = 0; jt < 4; ++jt)
                    acc[f][jt] = __builtin_amdgcn_mfma_f32_16x16x32_bf16(
                        af, bq[jt], acc[f][jt], 0, 0, 0);
            }
        }
    }

    // ---- phase 2: column softmax over i (lane's column j = jt*16 + l15)
    float mx[4];
#pragma unroll
    for (int jt = 0; jt < 4; ++jt) {
        float m = -1e30f;
#pragma unroll
        for (int f = 0; f < 8; ++f)
#pragma unroll
            for (int r = 0; r < 4; ++r) m = fmaxf(m, acc[f][jt][r]);
        m = fmaxf(m, __shfl_xor(m, 16));
        m = fmaxf(m, __shfl_xor(m, 32));
        mx[jt] = m;
    }
    if (l < 16) {
#pragma unroll
        for (int jt = 0; jt < 4; ++jt) wred[w * 64 + jt * 16 + l] = mx[jt];
    }
    __syncthreads();
    if (t < 64) {
        float m = wred[t];
#pragma unroll
        for (int ww = 1; ww < 8; ++ww) m = fmaxf(m, wred[ww * 64 + t]);
        colv[t] = m;
    }
    __syncthreads();

    float sm[4];
#pragma unroll
    for (int jt = 0; jt < 4; ++jt) {
        const float cm = colv[jt * 16 + l15];
        float s = 0.f;
#pragma unroll
        for (int f = 0; f < 8; ++f)
#pragma unroll
            for (int r = 0; r < 4; ++r) {
                float e = __expf(acc[f][jt][r] - cm);
                acc[f][jt][r] = e;
                s += e;
            }
        s += __shfl_xor(s, 16);
        s += __shfl_xor(s, 32);
        sm[jt] = s;
    }
    if (l < 16) {
#pragma unroll
        for (int jt = 0; jt < 4; ++jt) wred[w * 64 + jt * 16 + l] = sm[jt];
    }
    __syncthreads();
    if (t < 64) {
        float s = 0.f;
#pragma unroll
        for (int ww = 0; ww < 8; ++ww) s += wred[ww * 64 + t];
        colv[t] = 1.0f / s;
    }
    __syncthreads();

    // ---- phase 3: normalize; write attn (fp32) + P (bf16, swizzled [j][i])
    float* aout = attn + (size_t)n * HWD * HWD + jb * 64;
#pragma unroll
    for (int jt = 0; jt < 4; ++jt) {
        const int j = jt * 16 + l15;
        const float inv = colv[j];
#pragma unroll
        for (int f = 0; f < 8; ++f) {
            const int i0 = ibase + f * 16 + lg * 4;
            float p0 = acc[f][jt][0] * inv;
            float p1 = acc[f][jt][1] * inv;
            float p2 = acc[f][jt][2] * inv;
            float p3 = acc[f][jt][3] * inv;
            aout[(size_t)(i0 + 0) * HWD + j] = p0;
            aout[(size_t)(i0 + 1) * HWD + j] = p1;
            aout[(size_t)(i0 + 2) * HWD + j] = p2;
            aout[(size_t)(i0 + 3) * HWD + j] = p3;
            uint2 pw;
            pw.x = (f2b(p1) << 16) | f2b(p0);
            pw.y = (f2b(p3) << 16) | f2b(p2);
            const unsigned byte = (unsigned)j * 2048u + (((unsigned)i0 * 2u) ^ (((unsigned)j & 7u) << 4));
            *(uint2*)(smem + byte) = pw;
        }
    }

    // ---- phase 4: out = V * P. Wave w owns c-tile (w&3) and j-tiles {2*(w>>2), +1}.
    f32x4 oacc[2] = {};
    const int cm = w & 3, jn0 = (w >> 2) * 2;
    for (int ch = 0; ch < 8; ++ch) {
        __syncthreads();
#pragma unroll
        for (int p8 = 0; p8 < 4; ++p8) {
            const int idx = t + p8 * 512;           // 0..2047
            const int c = idx >> 5, i4 = (idx & 31) * 4;
            float4 vv = *(const float4*)&pv[nb + (size_t)c * HWD + ch * 128 + i4];
            uint2 pw;
            pw.x = (f2b(vv.y) << 16) | f2b(vv.x);
            pw.y = (f2b(vv.w) << 16) | f2b(vv.z);
            *(uint2*)&v_lds[c * 136 + i4] = pw;
        }
        __syncthreads();
#pragma unroll
        for (int ks = 0; ks < 4; ++ks) {
            bf16x8 av = *(const bf16x8*)&v_lds[(cm * 16 + l15) * 136 + ks * 32 + lg * 8];
#pragma unroll
            for (int u = 0; u < 2; ++u) {
                const int j = (jn0 + u) * 16 + l15;
                const unsigned ib = (unsigned)(ch * 128 + ks * 32 + lg * 8) * 2u;
                bf16x8 bp = *(const bf16x8*)(smem + (unsigned)j * 2048u + (ib ^ (((unsigned)j & 7u) << 4)));
                oacc[u] = __builtin_amdgcn_mfma_f32_16x16x32_bf16(av, bp, oacc[u], 0, 0, 0);
            }
        }
    }

    // ---- epilogue: x = qn + out
#pragma unroll
    for (int u = 0; u < 2; ++u) {
        const int j = (jn0 + u) * 16 + l15;
#pragma unroll
        for (int r = 0; r < 4; ++r) {
            const int c = cm * 16 + lg * 4 + r;
            const size_t o = nb + (size_t)c * HWD + jb * 64 + j;
            xout[o] = oacc[u][r] + qn[o];
        }
    }
}

// ---------------------------------------------------------------------------
extern "C" void kernel_launch(void* const* d_in, const int* in_sizes, int n_in,
                              void* d_out, int out_size, void* d_ws, size_t ws_size,
                              hipStream_t stream)
{
    const float* q  = (const float*)d_in[0];
    const float* k  = (const float*)d_in[1];
    const float* v  = (const float*)d_in[2];
    const float* w1 = (const float*)d_in[3];
    const float* b1 = (const float*)d_in[4];
    const float* w2 = (const float*)d_in[5];
    const float* b2 = (const float*)d_in[6];
    const float* w3 = (const float*)d_in[7];
    const float* b3 = (const float*)d_in[8];
    const float* wq = (const float*)d_in[9];
    const float* bq = (const float*)d_in[10];
    const float* wk = (const float*)d_in[11];
    const float* bk = (const float*)d_in[12];
    const float* wv = (const float*)d_in[13];
    const float* bv = (const float*)d_in[14];

    float* ws   = (float*)d_ws;
    float* part = ws;
    float* qn   = ws + 4096;
    float* pq   = qn + 2097152;
    float* pk   = pq + 2097152;
    float* pv   = pk + 2097152;

    float* xout = (float*)d_out;            // (N, C*H*W)
    float* attn = xout + 2097152;           // (N, HW, HW)

    k_stats<<<dim3(8, 3, 32), 256, 0, stream>>>(q, k, v, part);
    k_proj<<<dim3(16, 32), 256, 0, stream>>>(q, k, v, w1, b1, w2, b2, w3, b3,
                                             wq, bq, wk, bk, wv, bv,
                                             part, qn, pq, pk, pv);
    k_attn2<<<dim3(512), dim3(512), 0, stream>>>(pq, pk, pv, qn, xout, attn);
}

// Round 3
// 106.777 us; speedup vs baseline: 3.9981x; 1.0211x over previous
//
#include <hip/hip_runtime.h>
#include <math.h>

#define NB   32
#define CCH  64
#define HWD  1024
#define CHW  65536     // C*H*W per sample
#define EPSV 1e-5f

typedef __attribute__((ext_vector_type(8))) short bf16x8;
typedef __attribute__((ext_vector_type(4))) float f32x4;

__device__ __forceinline__ unsigned f2b(float x) {
    union { float f; unsigned u; } v; v.f = x;
    return (v.u + 0x7fffu + ((v.u >> 16) & 1u)) >> 16;   // RNE bf16 bits
}

// ---------------------------------------------------------------------------
// Kernel 1: partial LN stats. grid (chunk=8, which=3, n=32), block 256.
// ---------------------------------------------------------------------------
__global__ __launch_bounds__(256)
void k_stats(const float* __restrict__ q, const float* __restrict__ k,
             const float* __restrict__ v, float* __restrict__ part)
{
    const int chunk = blockIdx.x, which = blockIdx.y, n = blockIdx.z;
    const float* x = (which == 0) ? q : (which == 1 ? k : v);
    const float4* x4 = (const float4*)(x + (size_t)n * CHW) + chunk * 2048;
    float s = 0.f, ss = 0.f;
#pragma unroll
    for (int i = 0; i < 8; ++i) {
        float4 t = x4[threadIdx.x + i * 256];
        s  += t.x + t.y + t.z + t.w;
        ss += t.x * t.x + t.y * t.y + t.z * t.z + t.w * t.w;
    }
    __shared__ float rs[256], rss[256];
    rs[threadIdx.x] = s; rss[threadIdx.x] = ss;
    __syncthreads();
    for (int off = 128; off > 0; off >>= 1) {
        if (threadIdx.x < off) {
            rs[threadIdx.x]  += rs[threadIdx.x + off];
            rss[threadIdx.x] += rss[threadIdx.x + off];
        }
        __syncthreads();
    }
    if (threadIdx.x == 0) {
        const int b = (n * 3 + which) * 8 + chunk;
        part[b * 2 + 0] = rs[0];
        part[b * 2 + 1] = rss[0];
    }
}

// ---------------------------------------------------------------------------
// Kernel 2: finish stats + LayerNorm + 1x1-conv projections.
// grid (pt=16, n=32), block 256.
// Outputs: qn fp32 [c][pix];  pqt bf16 [pix][c] (pre-scaled 1/8);
//          pkt bf16 [pix][c];  pvb bf16 [c][pix].
// ---------------------------------------------------------------------------
__global__ __launch_bounds__(256)
void k_proj(const float* __restrict__ q,  const float* __restrict__ k,  const float* __restrict__ v,
            const float* __restrict__ w1, const float* __restrict__ b1,
            const float* __restrict__ w2, const float* __restrict__ b2,
            const float* __restrict__ w3, const float* __restrict__ b3,
            const float* __restrict__ wq, const float* __restrict__ bq,
            const float* __restrict__ wk, const float* __restrict__ bk,
            const float* __restrict__ wv, const float* __restrict__ bv,
            const float* __restrict__ part,
            float* __restrict__ qn, short* __restrict__ pqt,
            short* __restrict__ pkt, short* __restrict__ pvb)
{
    __shared__ float xn[3][64][68];
    __shared__ float wt[3][64][68];
    __shared__ float musd[6];
    const int pt = blockIdx.x, n = blockIdx.y;
    const int t = threadIdx.x;

    if (t < 3) {
        float s = 0.f, ss = 0.f;
#pragma unroll
        for (int cidx = 0; cidx < 8; ++cidx) {
            const int b = (n * 3 + t) * 8 + cidx;
            s  += part[b * 2 + 0];
            ss += part[b * 2 + 1];
        }
        const float mu = s * (1.0f / CHW);
        musd[t * 2 + 0] = mu;
        musd[t * 2 + 1] = rsqrtf(ss * (1.0f / CHW) - mu * mu + EPSV);
    }

    const float* pw[3] = {wq, wk, wv};
#pragma unroll
    for (int tt = 0; tt < 3; ++tt)
        for (int idx = t; idx < 4096; idx += 256) {
            const int o = idx >> 6, c = idx & 63;
            wt[tt][c][o] = pw[tt][idx];
        }
    __syncthreads();

    const float* src[3] = {q, k, v};
    const float* lw[3]  = {w1, w2, w3};
    const float* lb[3]  = {b1, b2, b3};
#pragma unroll
    for (int tt = 0; tt < 3; ++tt) {
        const float mu = musd[tt * 2], is = musd[tt * 2 + 1];
        for (int idx = t; idx < 1024; idx += 256) {
            const int c = idx >> 4, p4 = idx & 15;
            const int gi = c * HWD + pt * 64 + p4 * 4;
            float4 xv = *(const float4*)&src[tt][(size_t)n * CHW + gi];
            float4 w4 = *(const float4*)&lw[tt][gi];
            float4 b4 = *(const float4*)&lb[tt][gi];
            float4 r;
            r.x = (xv.x - mu) * is * w4.x + b4.x;
            r.y = (xv.y - mu) * is * w4.y + b4.y;
            r.z = (xv.z - mu) * is * w4.z + b4.z;
            r.w = (xv.w - mu) * is * w4.w + b4.w;
            *(float4*)&xn[tt][c][p4 * 4] = r;
            if (tt == 0) *(float4*)&qn[(size_t)n * CHW + gi] = r;
        }
    }
    __syncthreads();

    const int p   = t & 63;
    const int ob  = (t >> 6) * 16;
    const int pix = pt * 64 + p;
    const float* pbias[3] = {bq, bk, bv};
#pragma unroll
    for (int tt = 0; tt < 3; ++tt) {
        float acc[16];
#pragma unroll
        for (int i = 0; i < 16; ++i) acc[i] = pbias[tt][ob + i];
#pragma unroll 4
        for (int c = 0; c < 64; ++c) {
            const float xv = xn[tt][c][p];
#pragma unroll
            for (int o4 = 0; o4 < 4; ++o4) {
                float4 w4 = *(const float4*)&wt[tt][c][ob + o4 * 4];
                acc[o4 * 4 + 0] += w4.x * xv;
                acc[o4 * 4 + 1] += w4.y * xv;
                acc[o4 * 4 + 2] += w4.z * xv;
                acc[o4 * 4 + 3] += w4.w * xv;
            }
        }
        if (tt == 2) {          // V: [c][pix] bf16
#pragma unroll
            for (int i = 0; i < 16; ++i)
                pvb[(size_t)n * CHW + (ob + i) * HWD + pix] = (short)f2b(acc[i]);
        } else {                // Q^T / K^T: [pix][c] bf16 (Q pre-scaled 1/8)
            const float sc = (tt == 0) ? 0.125f : 1.0f;
            unsigned u[8];
#pragma unroll
            for (int i = 0; i < 8; ++i)
                u[i] = (f2b(acc[2 * i + 1] * sc) << 16) | f2b(acc[2 * i] * sc);
            short* dst = (tt == 0) ? pqt : pkt;
            *(uint4*)&dst[(size_t)n * CHW + pix * 64 + ob]     = *(uint4*)&u[0];
            *(uint4*)&dst[(size_t)n * CHW + pix * 64 + ob + 8] = *(uint4*)&u[4];
        }
    }
}

// ---------------------------------------------------------------------------
// Kernel 3 (MFMA): fused attention. One block per (n, 64-column tile).
// 512 threads = 8 waves. Wave w computes S rows i in [w*128, w*128+128).
//   LDS: p_lds  [64 j][1024 i] bf16, row 2048B, XOR-swizzled (131072 B)
//        q_lds  [64 j][72 c]   bf16 (Q^T, pre-scaled 1/8)    (9216 B)
//        wredA/wredB [8][64] f32  (max / sum partials)
// 4 barriers total; V and K fragments are direct global->reg bf16x8 loads.
// ---------------------------------------------------------------------------
__global__ __launch_bounds__(512, 2)
void k_attn2(const short* __restrict__ pqt, const short* __restrict__ pkt,
             const short* __restrict__ pvb, const float* __restrict__ qn,
             float* __restrict__ xout, float* __restrict__ attn)
{
    __shared__ __align__(16) char smem[131072 + 9216 + 4096];
    short* q_lds = (short*)(smem + 131072);
    float* wredA = (float*)(smem + 131072 + 9216);
    float* wredB = wredA + 512;

    // XCD-bijective swizzle: 512 wgs = 8 XCDs x 64; 4 consecutive samples/XCD
    const int wg  = blockIdx.x;
    const int xcd = wg & 7, lid = wg >> 3;
    const int n   = xcd * 4 + (lid >> 4);
    const int jb  = lid & 15;
    const size_t nb = (size_t)n * CHW;
    const int t = threadIdx.x;
    const int w = t >> 6;
    const int l = t & 63;
    const int l15 = l & 15, lg = l >> 4;
    const int ibase = w * 128;

    // ---- stage Q^T tile: q_lds[j][c] (one bf16x8 per thread)
    {
        const int j = t >> 3, c8 = (t & 7) * 8;
        *(bf16x8*)&q_lds[j * 72 + c8] =
            *(const bf16x8*)&pqt[nb + (size_t)(jb * 64 + j) * 64 + c8];
    }
    __syncthreads();

    // ---- phase 1: S = K^T Q   (acc[f][jt], f = i-frag 0..7, jt = j-frag 0..3)
    f32x4 acc[8][4] = {};
#pragma unroll
    for (int ks = 0; ks < 2; ++ks) {
        bf16x8 bq[4];
#pragma unroll
        for (int jt = 0; jt < 4; ++jt)
            bq[jt] = *(const bf16x8*)&q_lds[(jt * 16 + l15) * 72 + ks * 32 + lg * 8];
#pragma unroll
        for (int f = 0; f < 8; ++f) {
            const int i = ibase + f * 16 + l15;
            bf16x8 af = *(const bf16x8*)&pkt[nb + (size_t)i * 64 + ks * 32 + lg * 8];
#pragma unroll
            for (int jt = 0; jt < 4; ++jt)
                acc[f][jt] = __builtin_amdgcn_mfma_f32_16x16x32_bf16(
                    af, bq[jt], acc[f][jt], 0, 0, 0);
        }
    }

    // ---- phase 2: column softmax over i (lane's column j = jt*16 + l15)
    {
        float mx[4];
#pragma unroll
        for (int jt = 0; jt < 4; ++jt) {
            float m = -1e30f;
#pragma unroll
            for (int f = 0; f < 8; ++f)
#pragma unroll
                for (int r = 0; r < 4; ++r) m = fmaxf(m, acc[f][jt][r]);
            m = fmaxf(m, __shfl_xor(m, 16));
            m = fmaxf(m, __shfl_xor(m, 32));
            mx[jt] = m;
        }
        if (l < 16) {
#pragma unroll
            for (int jt = 0; jt < 4; ++jt) wredA[w * 64 + jt * 16 + l] = mx[jt];
        }
    }
    __syncthreads();

    float sm[4];
#pragma unroll
    for (int jt = 0; jt < 4; ++jt) {
        const int j = jt * 16 + l15;
        float cm = wredA[j];
#pragma unroll
        for (int ww = 1; ww < 8; ++ww) cm = fmaxf(cm, wredA[ww * 64 + j]);
        float s = 0.f;
#pragma unroll
        for (int f = 0; f < 8; ++f)
#pragma unroll
            for (int r = 0; r < 4; ++r) {
                float e = __expf(acc[f][jt][r] - cm);
                acc[f][jt][r] = e;
                s += e;
            }
        s += __shfl_xor(s, 16);
        s += __shfl_xor(s, 32);
        sm[jt] = s;
    }
    if (l < 16) {
#pragma unroll
        for (int jt = 0; jt < 4; ++jt) wredB[w * 64 + jt * 16 + l] = sm[jt];
    }
    __syncthreads();

    // ---- phase 3: normalize; write attn (fp32) + P (bf16, swizzled [j][i])
    float* aout = attn + (size_t)n * HWD * HWD + jb * 64;
#pragma unroll
    for (int jt = 0; jt < 4; ++jt) {
        const int j = jt * 16 + l15;
        float s = wredB[j];
#pragma unroll
        for (int ww = 1; ww < 8; ++ww) s += wredB[ww * 64 + j];
        const float inv = 1.0f / s;
#pragma unroll
        for (int f = 0; f < 8; ++f) {
            const int i0 = ibase + f * 16 + lg * 4;
            float p0 = acc[f][jt][0] * inv;
            float p1 = acc[f][jt][1] * inv;
            float p2 = acc[f][jt][2] * inv;
            float p3 = acc[f][jt][3] * inv;
            aout[(size_t)(i0 + 0) * HWD + j] = p0;
            aout[(size_t)(i0 + 1) * HWD + j] = p1;
            aout[(size_t)(i0 + 2) * HWD + j] = p2;
            aout[(size_t)(i0 + 3) * HWD + j] = p3;
            uint2 pw;
            pw.x = (f2b(p1) << 16) | f2b(p0);
            pw.y = (f2b(p3) << 16) | f2b(p2);
            const unsigned byte = (unsigned)j * 2048u + (((unsigned)i0 * 2u) ^ (((unsigned)j & 7u) << 4));
            *(uint2*)(smem + byte) = pw;
        }
    }
    __syncthreads();

    // ---- phase 4: out = V * P (V direct global->reg; no barriers).
    f32x4 oacc[2] = {};
    const int cm = w & 3, jn0 = (w >> 2) * 2;
#pragma unroll 4
    for (int ks = 0; ks < 32; ++ks) {
        bf16x8 av = *(const bf16x8*)&pvb[nb + (size_t)(cm * 16 + l15) * HWD + ks * 32 + lg * 8];
#pragma unroll
        for (int u = 0; u < 2; ++u) {
            const int j = (jn0 + u) * 16 + l15;
            const unsigned ib = (unsigned)(ks * 32 + lg * 8) * 2u;
            bf16x8 bp = *(const bf16x8*)(smem + (unsigned)j * 2048u + (ib ^ (((unsigned)j & 7u) << 4)));
            oacc[u] = __builtin_amdgcn_mfma_f32_16x16x32_bf16(av, bp, oacc[u], 0, 0, 0);
        }
    }

    // ---- epilogue: x = qn + out
#pragma unroll
    for (int u = 0; u < 2; ++u) {
        const int j = (jn0 + u) * 16 + l15;
#pragma unroll
        for (int r = 0; r < 4; ++r) {
            const int c = cm * 16 + lg * 4 + r;
            const size_t o = nb + (size_t)c * HWD + jb * 64 + j;
            xout[o] = oacc[u][r] + qn[o];
        }
    }
}

// ---------------------------------------------------------------------------
extern "C" void kernel_launch(void* const* d_in, const int* in_sizes, int n_in,
                              void* d_out, int out_size, void* d_ws, size_t ws_size,
                              hipStream_t stream)
{
    const float* q  = (const float*)d_in[0];
    const float* k  = (const float*)d_in[1];
    const float* v  = (const float*)d_in[2];
    const float* w1 = (const float*)d_in[3];
    const float* b1 = (const float*)d_in[4];
    const float* w2 = (const float*)d_in[5];
    const float* b2 = (const float*)d_in[6];
    const float* w3 = (const float*)d_in[7];
    const float* b3 = (const float*)d_in[8];
    const float* wq = (const float*)d_in[9];
    const float* bq = (const float*)d_in[10];
    const float* wk = (const float*)d_in[11];
    const float* bk = (const float*)d_in[12];
    const float* wv = (const float*)d_in[13];
    const float* bv = (const float*)d_in[14];

    // ws layout: part fp32 [1536] @0; qn fp32 @4096; pqt/pkt/pvb bf16 after.
    float* ws   = (float*)d_ws;
    float* part = ws;
    float* qn   = ws + 4096;
    short* pqt  = (short*)(qn + 2097152);
    short* pkt  = pqt + 2097152;
    short* pvb  = pkt + 2097152;

    float* xout = (float*)d_out;            // (N, C*H*W)
    float* attn = xout + 2097152;           // (N, HW, HW)

    k_stats<<<dim3(8, 3, 32), 256, 0, stream>>>(q, k, v, part);
    k_proj<<<dim3(16, 32), 256, 0, stream>>>(q, k, v, w1, b1, w2, b2, w3, b3,
                                             wq, bq, wk, bk, wv, bv,
                                             part, qn, pqt, pkt, pvb);
    k_attn2<<<dim3(512), dim3(512), 0, stream>>>(pqt, pkt, pvb, qn, xout, attn);
}

// Round 4
// 99.622 us; speedup vs baseline: 4.2852x; 1.0718x over previous
//
#include <hip/hip_runtime.h>
#include <math.h>

#define NB   32
#define CCH  64
#define HWD  1024
#define CHW  65536     // C*H*W per sample
#define EPSV 1e-5f

typedef __attribute__((ext_vector_type(8))) short bf16x8;
typedef __attribute__((ext_vector_type(4))) float f32x4;

__device__ __forceinline__ unsigned f2b(float x) {
    union { float f; unsigned u; } v; v.f = x;
    return (v.u + 0x7fffu + ((v.u >> 16) & 1u)) >> 16;   // RNE bf16 bits
}

// ---------------------------------------------------------------------------
// Kernel 1: partial LN stats. grid (chunk=8, which=3, n=32), block 256.
// ---------------------------------------------------------------------------
__global__ __launch_bounds__(256)
void k_stats(const float* __restrict__ q, const float* __restrict__ k,
             const float* __restrict__ v, float* __restrict__ part)
{
    const int chunk = blockIdx.x, which = blockIdx.y, n = blockIdx.z;
    const float* x = (which == 0) ? q : (which == 1 ? k : v);
    const float4* x4 = (const float4*)(x + (size_t)n * CHW) + chunk * 2048;
    float s = 0.f, ss = 0.f;
#pragma unroll
    for (int i = 0; i < 8; ++i) {
        float4 t = x4[threadIdx.x + i * 256];
        s  += t.x + t.y + t.z + t.w;
        ss += t.x * t.x + t.y * t.y + t.z * t.z + t.w * t.w;
    }
    __shared__ float rs[256], rss[256];
    rs[threadIdx.x] = s; rss[threadIdx.x] = ss;
    __syncthreads();
    for (int off = 128; off > 0; off >>= 1) {
        if (threadIdx.x < off) {
            rs[threadIdx.x]  += rs[threadIdx.x + off];
            rss[threadIdx.x] += rss[threadIdx.x + off];
        }
        __syncthreads();
    }
    if (threadIdx.x == 0) {
        const int b = (n * 3 + which) * 8 + chunk;
        part[b * 2 + 0] = rs[0];
        part[b * 2 + 1] = rss[0];
    }
}

// ---------------------------------------------------------------------------
// Kernel 2: finish stats + LayerNorm + 1x1-conv projections.
// grid (pt=16, n=32), block 256. One shared xn/wt buffer, Q/K/V sequential:
// LDS = 35 KB -> 4 blocks/CU (was 104 KB -> 1).
// Outputs: qn fp32 [c][pix];  pqt bf16 [pix][c] (pre-scaled 1/8);
//          pkt bf16 [pix][c];  pvb bf16 [c][pix].
// ---------------------------------------------------------------------------
__global__ __launch_bounds__(256, 4)
void k_proj(const float* __restrict__ q,  const float* __restrict__ k,  const float* __restrict__ v,
            const float* __restrict__ w1, const float* __restrict__ b1,
            const float* __restrict__ w2, const float* __restrict__ b2,
            const float* __restrict__ w3, const float* __restrict__ b3,
            const float* __restrict__ wq, const float* __restrict__ bq,
            const float* __restrict__ wk, const float* __restrict__ bk,
            const float* __restrict__ wv, const float* __restrict__ bv,
            const float* __restrict__ part,
            float* __restrict__ qn, short* __restrict__ pqt,
            short* __restrict__ pkt, short* __restrict__ pvb)
{
    __shared__ float xn[64][68];
    __shared__ float wt[64][68];
    __shared__ float musd[6];
    const int pt = blockIdx.x, n = blockIdx.y;
    const int t = threadIdx.x;

    if (t < 3) {
        float s = 0.f, ss = 0.f;
#pragma unroll
        for (int cidx = 0; cidx < 8; ++cidx) {
            const int b = (n * 3 + t) * 8 + cidx;
            s  += part[b * 2 + 0];
            ss += part[b * 2 + 1];
        }
        const float mu = s * (1.0f / CHW);
        musd[t * 2 + 0] = mu;
        musd[t * 2 + 1] = rsqrtf(ss * (1.0f / CHW) - mu * mu + EPSV);
    }
    __syncthreads();

    const float* src[3]   = {q, k, v};
    const float* lw[3]    = {w1, w2, w3};
    const float* lb[3]    = {b1, b2, b3};
    const float* pw[3]    = {wq, wk, wv};
    const float* pbias[3] = {bq, bk, bv};
    const int p   = t & 63;
    const int ob  = (t >> 6) * 16;
    const int pix = pt * 64 + p;

    for (int tt = 0; tt < 3; ++tt) {
        // stage transposed proj weights
        for (int idx = t; idx < 4096; idx += 256) {
            const int o = idx >> 6, c = idx & 63;
            wt[c][o] = pw[tt][idx];
        }
        // normalize input tile into LDS (and write qn for residual)
        const float mu = musd[tt * 2], is = musd[tt * 2 + 1];
        for (int idx = t; idx < 1024; idx += 256) {
            const int c = idx >> 4, p4 = idx & 15;
            const int gi = c * HWD + pt * 64 + p4 * 4;
            float4 xv = *(const float4*)&src[tt][(size_t)n * CHW + gi];
            float4 w4 = *(const float4*)&lw[tt][gi];
            float4 b4 = *(const float4*)&lb[tt][gi];
            float4 r;
            r.x = (xv.x - mu) * is * w4.x + b4.x;
            r.y = (xv.y - mu) * is * w4.y + b4.y;
            r.z = (xv.z - mu) * is * w4.z + b4.z;
            r.w = (xv.w - mu) * is * w4.w + b4.w;
            *(float4*)&xn[c][p4 * 4] = r;
            if (tt == 0) *(float4*)&qn[(size_t)n * CHW + gi] = r;
        }
        __syncthreads();

        float acc[16];
#pragma unroll
        for (int i = 0; i < 16; ++i) acc[i] = pbias[tt][ob + i];
#pragma unroll 4
        for (int c = 0; c < 64; ++c) {
            const float xv = xn[c][p];
#pragma unroll
            for (int o4 = 0; o4 < 4; ++o4) {
                float4 w4 = *(const float4*)&wt[c][ob + o4 * 4];
                acc[o4 * 4 + 0] += w4.x * xv;
                acc[o4 * 4 + 1] += w4.y * xv;
                acc[o4 * 4 + 2] += w4.z * xv;
                acc[o4 * 4 + 3] += w4.w * xv;
            }
        }
        if (tt == 2) {          // V: [c][pix] bf16
#pragma unroll
            for (int i = 0; i < 16; ++i)
                pvb[(size_t)n * CHW + (ob + i) * HWD + pix] = (short)f2b(acc[i]);
        } else {                // Q^T / K^T: [pix][c] bf16 (Q pre-scaled 1/8)
            const float sc = (tt == 0) ? 0.125f : 1.0f;
            unsigned u[8];
#pragma unroll
            for (int i = 0; i < 8; ++i)
                u[i] = (f2b(acc[2 * i + 1] * sc) << 16) | f2b(acc[2 * i] * sc);
            short* dst = (tt == 0) ? pqt : pkt;
            *(uint4*)&dst[(size_t)n * CHW + pix * 64 + ob]     = *(uint4*)&u[0];
            *(uint4*)&dst[(size_t)n * CHW + pix * 64 + ob + 8] = *(uint4*)&u[4];
        }
        __syncthreads();        // protect xn/wt before next tt overwrites
    }
}

// ---------------------------------------------------------------------------
// Kernel 3 (MFMA): fused attention. One block per (n, 32-column tile).
// 512 threads = 8 waves. Wave w computes S rows i in [w*128, w*128+128).
//   LDS: p_lds  [32 j][1024 i] bf16, row 2048B, XOR-swizzled  (65536 B)
//        q_lds  [32 j][72 c]   bf16 (Q^T, pre-scaled 1/8)     (4608 B)
//        wredA/wredB [8][32] f32                              (2048 B)
//   total 72192 B -> 2 blocks/CU; __launch_bounds__(512,4) caps VGPR at 128.
// ---------------------------------------------------------------------------
__global__ __launch_bounds__(512, 4)
void k_attn2(const short* __restrict__ pqt, const short* __restrict__ pkt,
             const short* __restrict__ pvb, const float* __restrict__ qn,
             float* __restrict__ xout, float* __restrict__ attn)
{
    __shared__ __align__(16) char smem[65536 + 4608 + 2048];
    short* q_lds = (short*)(smem + 65536);
    float* wredA = (float*)(smem + 65536 + 4608);
    float* wredB = wredA + 256;

    // XCD-bijective swizzle: 1024 wgs = 8 XCDs x 128; 4 consecutive samples/XCD
    const int wg  = blockIdx.x;
    const int xcd = wg & 7, lid = wg >> 3;
    const int n   = xcd * 4 + (lid >> 5);
    const int jb  = lid & 31;                 // 32-col tile index
    const size_t nb = (size_t)n * CHW;
    const int t = threadIdx.x;
    const int w = t >> 6;
    const int l = t & 63;
    const int l15 = l & 15, lg = l >> 4;
    const int ibase = w * 128;

    // ---- stage Q^T tile: q_lds[j][c] (32 j x 64 c, first 256 threads)
    if (t < 256) {
        const int j = t >> 3, c8 = (t & 7) * 8;
        *(bf16x8*)&q_lds[j * 72 + c8] =
            *(const bf16x8*)&pqt[nb + (size_t)(jb * 32 + j) * 64 + c8];
    }
    __syncthreads();

    // ---- phase 1: S = K^T Q   (acc[f][jt], f = i-frag 0..7, jt = j-frag 0..1)
    f32x4 acc[8][2] = {};
#pragma unroll
    for (int ks = 0; ks < 2; ++ks) {
        bf16x8 bqf[2];
#pragma unroll
        for (int jt = 0; jt < 2; ++jt)
            bqf[jt] = *(const bf16x8*)&q_lds[(jt * 16 + l15) * 72 + ks * 32 + lg * 8];
#pragma unroll
        for (int f = 0; f < 8; ++f) {
            const int i = ibase + f * 16 + l15;
            bf16x8 af = *(const bf16x8*)&pkt[nb + (size_t)i * 64 + ks * 32 + lg * 8];
#pragma unroll
            for (int jt = 0; jt < 2; ++jt)
                acc[f][jt] = __builtin_amdgcn_mfma_f32_16x16x32_bf16(
                    af, bqf[jt], acc[f][jt], 0, 0, 0);
        }
    }

    // ---- phase 2: column softmax over i (lane's column j = jt*16 + l15)
    {
        float mx[2];
#pragma unroll
        for (int jt = 0; jt < 2; ++jt) {
            float m = -1e30f;
#pragma unroll
            for (int f = 0; f < 8; ++f)
#pragma unroll
                for (int r = 0; r < 4; ++r) m = fmaxf(m, acc[f][jt][r]);
            m = fmaxf(m, __shfl_xor(m, 16));
            m = fmaxf(m, __shfl_xor(m, 32));
            mx[jt] = m;
        }
        if (l < 16) {
#pragma unroll
            for (int jt = 0; jt < 2; ++jt) wredA[w * 32 + jt * 16 + l] = mx[jt];
        }
    }
    __syncthreads();

    float sm[2];
#pragma unroll
    for (int jt = 0; jt < 2; ++jt) {
        const int j = jt * 16 + l15;
        float cm = wredA[j];
#pragma unroll
        for (int ww = 1; ww < 8; ++ww) cm = fmaxf(cm, wredA[ww * 32 + j]);
        float s = 0.f;
#pragma unroll
        for (int f = 0; f < 8; ++f)
#pragma unroll
            for (int r = 0; r < 4; ++r) {
                float e = __expf(acc[f][jt][r] - cm);
                acc[f][jt][r] = e;
                s += e;
            }
        s += __shfl_xor(s, 16);
        s += __shfl_xor(s, 32);
        sm[jt] = s;
    }
    if (l < 16) {
#pragma unroll
        for (int jt = 0; jt < 2; ++jt) wredB[w * 32 + jt * 16 + l] = sm[jt];
    }
    __syncthreads();

    // ---- phase 3: normalize; write attn (fp32) + P (bf16, swizzled [j][i])
    float* aout = attn + (size_t)n * HWD * HWD + jb * 32;
#pragma unroll
    for (int jt = 0; jt < 2; ++jt) {
        const int j = jt * 16 + l15;
        float s = wredB[j];
#pragma unroll
        for (int ww = 1; ww < 8; ++ww) s += wredB[ww * 32 + j];
        const float inv = 1.0f / s;
#pragma unroll
        for (int f = 0; f < 8; ++f) {
            const int i0 = ibase + f * 16 + lg * 4;
            float p0 = acc[f][jt][0] * inv;
            float p1 = acc[f][jt][1] * inv;
            float p2 = acc[f][jt][2] * inv;
            float p3 = acc[f][jt][3] * inv;
            aout[(size_t)(i0 + 0) * HWD + j] = p0;
            aout[(size_t)(i0 + 1) * HWD + j] = p1;
            aout[(size_t)(i0 + 2) * HWD + j] = p2;
            aout[(size_t)(i0 + 3) * HWD + j] = p3;
            uint2 pw;
            pw.x = (f2b(p1) << 16) | f2b(p0);
            pw.y = (f2b(p3) << 16) | f2b(p2);
            const unsigned byte = (unsigned)j * 2048u + (((unsigned)i0 * 2u) ^ (((unsigned)j & 7u) << 4));
            *(uint2*)(smem + byte) = pw;
        }
    }
    __syncthreads();

    // ---- phase 4: out = V * P. Wave w owns c-tile (w&3), j-tile (w>>2).
    f32x4 oacc = {};
    const int cm = w & 3, jn = w >> 2;
    const int j = jn * 16 + l15;
    __builtin_amdgcn_s_setprio(1);
#pragma unroll 4
    for (int ks = 0; ks < 32; ++ks) {
        bf16x8 av = *(const bf16x8*)&pvb[nb + (size_t)(cm * 16 + l15) * HWD + ks * 32 + lg * 8];
        const unsigned ib = (unsigned)(ks * 32 + lg * 8) * 2u;
        bf16x8 bp = *(const bf16x8*)(smem + (unsigned)j * 2048u + (ib ^ (((unsigned)j & 7u) << 4)));
        oacc = __builtin_amdgcn_mfma_f32_16x16x32_bf16(av, bp, oacc, 0, 0, 0);
    }
    __builtin_amdgcn_s_setprio(0);

    // ---- epilogue: x = qn + out
#pragma unroll
    for (int r = 0; r < 4; ++r) {
        const int c = cm * 16 + lg * 4 + r;
        const size_t o = nb + (size_t)c * HWD + jb * 32 + j;
        xout[o] = oacc[r] + qn[o];
    }
}

// ---------------------------------------------------------------------------
extern "C" void kernel_launch(void* const* d_in, const int* in_sizes, int n_in,
                              void* d_out, int out_size, void* d_ws, size_t ws_size,
                              hipStream_t stream)
{
    const float* q  = (const float*)d_in[0];
    const float* k  = (const float*)d_in[1];
    const float* v  = (const float*)d_in[2];
    const float* w1 = (const float*)d_in[3];
    const float* b1 = (const float*)d_in[4];
    const float* w2 = (const float*)d_in[5];
    const float* b2 = (const float*)d_in[6];
    const float* w3 = (const float*)d_in[7];
    const float* b3 = (const float*)d_in[8];
    const float* wq = (const float*)d_in[9];
    const float* bq = (const float*)d_in[10];
    const float* wk = (const float*)d_in[11];
    const float* bk = (const float*)d_in[12];
    const float* wv = (const float*)d_in[13];
    const float* bv = (const float*)d_in[14];

    // ws layout: part fp32 [1536] @0; qn fp32 @4096; pqt/pkt/pvb bf16 after.
    float* ws   = (float*)d_ws;
    float* part = ws;
    float* qn   = ws + 4096;
    short* pqt  = (short*)(qn + 2097152);
    short* pkt  = pqt + 2097152;
    short* pvb  = pkt + 2097152;

    float* xout = (float*)d_out;            // (N, C*H*W)
    float* attn = xout + 2097152;           // (N, HW, HW)

    k_stats<<<dim3(8, 3, 32), 256, 0, stream>>>(q, k, v, part);
    k_proj<<<dim3(16, 32), 256, 0, stream>>>(q, k, v, w1, b1, w2, b2, w3, b3,
                                             wq, bq, wk, bk, wv, bv,
                                             part, qn, pqt, pkt, pvb);
    k_attn2<<<dim3(1024), dim3(512), 0, stream>>>(pqt, pkt, pvb, qn, xout, attn);
}